// Round 5
// baseline (594.969 us; speedup 1.0000x reference)
//
#include <hip/hip_runtime.h>
#include <math.h>

#define Bn 32
#define Tn 64
#define An 6
#define Ln 32
#define Hn 128
#define FDn 256
#define Nimg (Bn*Tn)   // 2048

typedef __attribute__((ext_vector_type(8))) short frag_ab;     // 8 bf16
typedef __attribute__((ext_vector_type(4))) float frag_cd;     // 4 fp32
typedef _Float16 h2_t __attribute__((ext_vector_type(2)));

__device__ __forceinline__ float sigmoid_fast(float x){
  return __builtin_amdgcn_rcpf(1.f + __expf(-x));
}
__device__ __forceinline__ float tanh_fast(float x){
  float x2 = fminf(fmaxf(2.f*x, -30.f), 30.f);
  float e = __expf(x2);
  return (e - 1.f) * __builtin_amdgcn_rcpf(e + 1.f);
}

__device__ __forceinline__ unsigned short f2bf(float f){
  unsigned int u = __float_as_uint(f);
  unsigned int r = (u + 0x7fffu + ((u >> 16) & 1u)) >> 16;
  return (unsigned short)r;
}
__device__ __forceinline__ unsigned packh(float a, float b){
  union { h2_t h; unsigned u; } x;
  x.h = (h2_t){(_Float16)a, (_Float16)b};
  return x.u;
}
__device__ __forceinline__ float fdot2u(unsigned a, unsigned b, float c){
  union { unsigned u; h2_t h; } ua, ub;
  ua.u = a; ub.u = b;
#if __has_builtin(__builtin_amdgcn_fdot2)
  return __builtin_amdgcn_fdot2(ua.h, ub.h, c, false);
#else
  return c + (float)ua.h.x*(float)ub.h.x + (float)ua.h.y*(float)ub.h.y;
#endif
}
// barrier without vmcnt drain: global loads/stores in flight stay in flight
#define BAR_LDS() asm volatile("s_waitcnt lgkmcnt(0)\n\ts_barrier" ::: "memory")

// LDS fragment addressing with XOR row swizzle (units: unsigned short)
__device__ __forceinline__ int swz_w(int r, int p){
  return ((r >> 4) << 9) + (p << 7) + ((((r & 15) ^ (p << 2))) << 3);
}
__device__ __forceinline__ int swz_r(int f, int l){
  return (f << 9) + ((l >> 4) << 7) + ((((l & 15) ^ ((l >> 4) << 2))) << 3);
}

// ---------------------------------------------------------------------------
// states: (2048, 3, 64, 64) fp32 NCHW -> (2048, 64, 64, 4) bf16 NHWC (c3 = 0)
// ---------------------------------------------------------------------------
__global__ void __launch_bounds__(256)
states_nhwc_kernel(const float* __restrict__ src, unsigned short* __restrict__ dst)
{
  int idx = blockIdx.x*256 + threadIdx.x;      // 2048*4096
  int n = idx >> 12, pix = idx & 4095;
  const float* s = src + (size_t)n*3*4096 + pix;
  union { unsigned short e[4]; uint2 v; } u;
  u.e[0] = f2bf(s[0]); u.e[1] = f2bf(s[4096]); u.e[2] = f2bf(s[8192]); u.e[3] = 0;
  *(uint2*)(dst + (size_t)idx*4) = u.v;
}

// ---------------------------------------------------------------------------
// merged prep (unchanged layouts):
//   g_whh2 [c(64)][n(384)] : Whh row n, k-pair c
//   g_wihz [c(16)][n(384)] : Wih z-part (k 0..31)
//   g_pr2  [c(64)][o(64)]  : prior rows, k-pair c
//   g_po2  [c(64)][o(64)]  : post h-part rows, k-pair c
// ---------------------------------------------------------------------------
__global__ void __launch_bounds__(256)
prep2_kernel(const float* __restrict__ c1w, const float* __restrict__ c2w,
             const float* __restrict__ c3w, const float* __restrict__ c4w,
             const float* __restrict__ fcw,
             const float* __restrict__ gwhh, const float* __restrict__ gwih,
             const float* __restrict__ prw,  const float* __restrict__ pow_,
             unsigned short* __restrict__ w1p, unsigned short* __restrict__ w2p,
             unsigned short* __restrict__ w3p, unsigned short* __restrict__ w4p,
             unsigned short* __restrict__ wfcp,
             unsigned* __restrict__ g_whh2, unsigned* __restrict__ g_wihz,
             unsigned* __restrict__ g_pr2,  unsigned* __restrict__ g_po2)
{
  const int bid = blockIdx.x, tid = threadIdx.x;
  if (bid < 128){            // c2: (64,32,16) -> [k][tap*32+c]
    int idx = bid*256+tid;
    int k = idx >> 9, r = idx & 511, tap = r >> 5, c = r & 31;
    w2p[idx] = f2bf(c2w[k*512 + c*16 + tap]);
  } else if (bid < 640){     // c3: (128,64,16)
    int idx = (bid-128)*256+tid;
    int k = idx >> 10, r = idx & 1023, tap = r >> 6, c = r & 63;
    w3p[idx] = f2bf(c3w[k*1024 + c*16 + tap]);
  } else if (bid < 2688){    // c4: (256,128,16)
    int idx = (bid-640)*256+tid;
    int k = idx >> 11, r = idx & 2047, tap = r >> 7, c = r & 127;
    w4p[idx] = f2bf(c4w[k*2048 + c*16 + tap]);
  } else if (bid < 6784){    // fc: [o][sp*256+c] = src[o*4096 + c*16 + sp]
    int idx = (bid-2688)*256+tid;
    int o = idx >> 12, r = idx & 4095, sp = r >> 8, c = r & 255;
    wfcp[idx] = f2bf(fcw[o*4096 + c*16 + sp]);
  } else if (bid < 6792){    // c1: (32,3,16) -> [k][tap*4+c], c3=0
    int idx = (bid-6784)*256+tid;
    int k = idx >> 6, r = idx & 63, tap = r >> 2, c = r & 3;
    w1p[idx] = (c < 3) ? f2bf(c1w[k*48 + c*16 + tap]) : (unsigned short)0;
  } else if (bid < 6888){    // whh pack: 24576 uints, [c][n]
    int idx = (bid-6792)*256+tid;
    int c = idx / 384, i = idx - c*384;
    g_whh2[idx] = packh(gwhh[i*128 + 2*c], gwhh[i*128 + 2*c + 1]);
  } else if (bid < 6912){    // wih z-part pack: 6144 uints, [c][n]
    int idx = (bid-6888)*256+tid;
    int c = idx / 384, i = idx - c*384;
    g_wihz[idx] = packh(gwih[i*38 + 2*c], gwih[i*38 + 2*c + 1]);
  } else if (bid < 6928){    // prior pack: 4096 uints, [c][o]
    int idx = (bid-6912)*256+tid;
    int c = idx >> 6, o = idx & 63;
    g_pr2[idx] = packh(prw[o*128 + 2*c], prw[o*128 + 2*c + 1]);
  } else {                   // post h-part pack: 4096 uints, [c][o]
    int idx = (bid-6928)*256+tid;
    int c = idx >> 6, o = idx & 63;
    g_po2[idx] = packh(pow_[o*384 + 2*c], pow_[o*384 + 2*c + 1]);
  }
}

// GIA[bt][n] = bih[n] + a_t . Wih_a[n]   (f32, no recurrence)
__global__ void __launch_bounds__(384)
gia_kernel(const float* __restrict__ actions, const float* __restrict__ gwih,
           const float* __restrict__ bih, float* __restrict__ GIA)
{
  const int tid = threadIdx.x;
  const int bt0 = blockIdx.x * 8;
  __shared__ float ash[48];
  if (tid < 48) ash[tid] = actions[(size_t)bt0*6 + tid];
  float w6[6];
#pragma unroll
  for (int k = 0; k < 6; k++) w6[k] = gwih[tid*38 + 32 + k];
  const float bv = bih[tid];
  __syncthreads();
#pragma unroll
  for (int r = 0; r < 8; r++){
    float v = bv;
#pragma unroll
    for (int k = 0; k < 6; k++) v = fmaf(ash[r*6+k], w6[k], v);
    GIA[(size_t)(bt0 + r)*384 + tid] = v;
  }
}

// POF[bt][o] = po_b[o] + Wpo_f[o] . f_bt   (f32 GEMM 2048x64x256, no recurrence)
__global__ void __launch_bounds__(256)
pof_kernel(const float* __restrict__ feats, const float* __restrict__ po_w,
           const float* __restrict__ po_b, float* __restrict__ POF)
{
  const int tid = threadIdx.x;
  const int bt0 = blockIdx.x * 8;
  __shared__ __align__(16) float fsh[8*256];
  const float4* fsrc = (const float4*)(feats + (size_t)bt0*256);
  ((float4*)fsh)[tid]       = fsrc[tid];
  ((float4*)fsh)[tid + 256] = fsrc[tid + 256];
  __syncthreads();
  const float4* w4 = (const float4*)po_w;
  const float4* f4 = (const float4*)fsh;
#pragma unroll
  for (int i = 0; i < 2; i++){
    int item = tid + i*256;
    int row = item >> 6, o = item & 63;
    float4 acc = {0.f,0.f,0.f,0.f};
#pragma unroll 8
    for (int k = 0; k < 64; k++){
      float4 wv = w4[o*96 + 32 + k];
      float4 fv = f4[row*64 + k];
      acc.x = fmaf(wv.x, fv.x, acc.x);
      acc.y = fmaf(wv.y, fv.y, acc.y);
      acc.z = fmaf(wv.z, fv.z, acc.z);
      acc.w = fmaf(wv.w, fv.w, acc.w);
    }
    POF[(size_t)(bt0 + row)*64 + o] = (acc.x + acc.y) + (acc.z + acc.w) + po_b[o];
  }
}

// ---------------------------------------------------------------------------
// NHWC implicit-GEMM conv (k=4, s=2, p=1), MFMA 16x16x32 bf16.  (unchanged)
// ---------------------------------------------------------------------------
template<int Cin, int IN, int Kout, int OUT, int BN, int LOG_SPB>
__global__ void __launch_bounds__(256)
convN_mfma(const unsigned short* __restrict__ in,
           const unsigned short* __restrict__ wB,
           const float* __restrict__ bias,
           unsigned short* __restrict__ out)
{
  constexpr int SPB = OUT*OUT;
  constexpr int KD  = 16*Cin;
  constexpr int NCH = KD/32;
  constexpr int NFN = BN/32;
  constexpr int BFR = BN/16;
  constexpr int BSL = (BN*4 + 255)/256;
  __shared__ __align__(16) unsigned short Alds[2][8*512];
  __shared__ __align__(16) unsigned short Blds[2][BFR*512];

  const int tid = threadIdx.x;
  const int wave = tid >> 6, lane = tid & 63;
  const unsigned m0 = blockIdx.x * 128;
  const int n0 = blockIdx.y * BN;

  const int p = tid & 3;
  const unsigned short* baseA[2]; int oyA[2], oxA[2]; int AdstI[2];
#pragma unroll
  for (int h = 0; h < 2; h++){
    int r = (tid >> 2) + h*64;
    unsigned m = m0 + r;
    int nimg = m >> LOG_SPB;
    int sp = m & (SPB - 1);
    oyA[h] = sp / OUT; oxA[h] = sp & (OUT - 1);
    baseA[h] = in + (size_t)nimg * IN * IN * Cin;
    AdstI[h] = swz_w(r, p);
  }

  const unsigned short* BsrcH[BSL]; int BdstIH[BSL]; bool bActH[BSL];
#pragma unroll
  for (int h = 0; h < BSL; h++){
    int bn = (tid >> 2) + h*64, pb = tid & 3;
    bActH[h] = bn < BN;
    BsrcH[h] = wB + (size_t)(n0 + bn)*KD + pb*8;
    BdstIH[h] = swz_w(bn, pb);
  }

  const int mhalf = wave >> 1, nhalf = wave & 1;
  frag_cd acc[4][NFN];
#pragma unroll
  for (int i = 0; i < 4; i++)
#pragma unroll
    for (int j = 0; j < NFN; j++) acc[i][j] = (frag_cd){0.f,0.f,0.f,0.f};

  auto loadA = [&](int kt, int h) -> uint4 {
    if constexpr (Cin >= 32){
      constexpr int CPT = Cin/32;
      int tap = kt / CPT;
      int c0 = (kt - tap*CPT)*32;
      int kh = tap >> 2, kw = tap & 3;
      int iy = 2*oyA[h] - 1 + kh;
      int ix = 2*oxA[h] - 1 + kw;
      uint4 v = {0u,0u,0u,0u};
      if ((unsigned)iy < (unsigned)IN && (unsigned)ix < (unsigned)IN)
        v = *(const uint4*)(baseA[h] + ((iy*IN + ix)*Cin + c0 + p*8));
      return v;
    } else {
      int kh = kt*2 + (p >> 1);
      int kw0 = (p & 1)*2;
      int iy = 2*oyA[h] - 1 + kh;
      int ix0 = 2*oxA[h] - 1 + kw0;
      union { uint2 u2[2]; uint4 u4; } v; v.u4 = (uint4){0u,0u,0u,0u};
      bool iyok = (unsigned)iy < (unsigned)IN;
      const unsigned short* rowp = baseA[h] + iy*IN*4;
#pragma unroll
      for (int d = 0; d < 2; d++){
        int ix = ix0 + d;
        if (iyok && (unsigned)ix < (unsigned)IN) v.u2[d] = *(const uint2*)(rowp + ix*4);
      }
      return v.u4;
    }
  };

  const int rdoff = swz_r(0, lane);

  uint4 aR0 = loadA(0,0), aR1 = loadA(0,1);
  uint4 bR[BSL];
#pragma unroll
  for (int h = 0; h < BSL; h++)
    bR[h] = bActH[h] ? *(const uint4*)BsrcH[h] : (uint4){0u,0u,0u,0u};
  *(uint4*)&Alds[0][AdstI[0]] = aR0;
  *(uint4*)&Alds[0][AdstI[1]] = aR1;
#pragma unroll
  for (int h = 0; h < BSL; h++)
    if (bActH[h]) *(uint4*)&Blds[0][BdstIH[h]] = bR[h];
  if (NCH > 1){
    aR0 = loadA(1,0); aR1 = loadA(1,1);
#pragma unroll
    for (int h = 0; h < BSL; h++)
      if (bActH[h]) bR[h] = *(const uint4*)(BsrcH[h] + 32);
  }
  BAR_LDS();

#pragma unroll 2
  for (int kt = 0; kt < NCH; kt++){
    const int cur = kt & 1, nxt = cur ^ 1;
    if (kt + 1 < NCH){
      *(uint4*)&Alds[nxt][AdstI[0]] = aR0;
      *(uint4*)&Alds[nxt][AdstI[1]] = aR1;
#pragma unroll
      for (int h = 0; h < BSL; h++)
        if (bActH[h]) *(uint4*)&Blds[nxt][BdstIH[h]] = bR[h];
      if (kt + 2 < NCH){
        aR0 = loadA(kt+2, 0);
        aR1 = loadA(kt+2, 1);
#pragma unroll
        for (int h = 0; h < BSL; h++)
          if (bActH[h]) bR[h] = *(const uint4*)(BsrcH[h] + (kt+2)*32);
      }
    }
    frag_ab a[4], bf[NFN];
#pragma unroll
    for (int i = 0; i < 4; i++)
      a[i] = *(const frag_ab*)&Alds[cur][(((mhalf<<2) + i) << 9) + rdoff];
#pragma unroll
    for (int j = 0; j < NFN; j++)
      bf[j] = *(const frag_ab*)&Blds[cur][((nhalf*NFN + j) << 9) + rdoff];
#pragma unroll
    for (int i = 0; i < 4; i++)
#pragma unroll
      for (int j = 0; j < NFN; j++)
        acc[i][j] = __builtin_amdgcn_mfma_f32_16x16x32_bf16(a[i], bf[j], acc[i][j], 0, 0, 0);
    BAR_LDS();
  }

  const unsigned mb = m0 + mhalf*64 + ((lane >> 4) << 2);
#pragma unroll
  for (int j = 0; j < NFN; j++){
    const int kg = n0 + nhalf*(NFN*16) + j*16 + (lane & 15);
    const float bv = bias[kg];
#pragma unroll
    for (int i = 0; i < 4; i++){
#pragma unroll
      for (int r = 0; r < 4; r++){
        unsigned mg = mb + i*16 + r;
        out[(size_t)mg*Kout + kg] = f2bf(fmaxf(acc[i][j][r] + bv, 0.f));
      }
    }
  }
}

// ---------------------------------------------------------------------------
// FC GEMM: A (2048 x 4096) bf16, W (256 x 4096) permuted.  (unchanged)
// ---------------------------------------------------------------------------
__global__ void __launch_bounds__(256)
fc_mfma2(const unsigned short* __restrict__ A, const unsigned short* __restrict__ wB,
         const float* __restrict__ bias, float* __restrict__ outF)
{
  constexpr int KD = 4096, NCH = KD/32;
  __shared__ __align__(16) unsigned short Alds[2][4*512];
  __shared__ __align__(16) unsigned short Blds[2][4*512];

  const int tid = threadIdx.x, wave = tid >> 6, lane = tid & 63;
  const int m0 = blockIdx.x * 64, n0 = blockIdx.y * 64;
  const int r = tid >> 2, pc = tid & 3;
  const unsigned short* Asrc = A + (size_t)(m0 + r)*KD + pc*8;
  const unsigned short* Bsrc = wB + (size_t)(n0 + r)*KD + pc*8;
  const int wI = swz_w(r, pc);
  const int mh = wave >> 1, nh = wave & 1;
  const int rdoff = swz_r(0, lane);

  frag_cd acc[2][2];
#pragma unroll
  for (int i = 0; i < 2; i++)
#pragma unroll
    for (int j = 0; j < 2; j++) acc[i][j] = (frag_cd){0.f,0.f,0.f,0.f};

  uint4 aP = *(const uint4*)Asrc, bP = *(const uint4*)Bsrc;
  *(uint4*)&Alds[0][wI] = aP;
  *(uint4*)&Blds[0][wI] = bP;
  aP = *(const uint4*)(Asrc + 32);
  bP = *(const uint4*)(Bsrc + 32);
  BAR_LDS();

#pragma unroll 2
  for (int kt = 0; kt < NCH; kt++){
    const int cur = kt & 1, nxt = cur ^ 1;
    if (kt + 1 < NCH){
      *(uint4*)&Alds[nxt][wI] = aP;
      *(uint4*)&Blds[nxt][wI] = bP;
      if (kt + 2 < NCH){
        aP = *(const uint4*)(Asrc + (kt+2)*32);
        bP = *(const uint4*)(Bsrc + (kt+2)*32);
      }
    }
    frag_ab a[2], b[2];
#pragma unroll
    for (int i = 0; i < 2; i++) a[i] = *(const frag_ab*)&Alds[cur][(((mh<<1)+i) << 9) + rdoff];
#pragma unroll
    for (int j = 0; j < 2; j++) b[j] = *(const frag_ab*)&Blds[cur][(((nh<<1)+j) << 9) + rdoff];
#pragma unroll
    for (int i = 0; i < 2; i++)
#pragma unroll
      for (int j = 0; j < 2; j++)
        acc[i][j] = __builtin_amdgcn_mfma_f32_16x16x32_bf16(a[i], b[j], acc[i][j], 0, 0, 0);
    BAR_LDS();
  }

  const int mb = m0 + mh*32 + ((lane >> 4) << 2);
#pragma unroll
  for (int j = 0; j < 2; j++){
    const int kg = n0 + nh*32 + j*16 + (lane & 15);
    const float bv = bias[kg];
#pragma unroll
    for (int i = 0; i < 2; i++)
#pragma unroll
      for (int rr = 0; rr < 4; rr++)
        outF[(size_t)(mb + i*16 + rr)*256 + kg] = acc[i][j][rr] + bv;
  }
}

// ---------------------------------------------------------------------------
// RSSM scan v7: split-K across 768 threads (12 waves). kh = tid>=384,
// nn = tid%384. Per-thread state HALVED vs v6 so it fits under even a
// pessimistic ~96-VGPR budget with no spills (v6's 144-VGPR/64-SGPR demand
// was being spilled to scratch every step — VGPR=96 both with and without
// launch_bounds mods):
//   all threads: whhH[32] (k-half of Whh row nn) + wihzH[8] (z-dot half)
//   hsu[32] wave-uniform SGPRs (k-half of h)
//   wv0/wv6 (prior) + wv1/wv7 (post): wpx[32], kh split WITHIN the wave
//   (lanes l and l^32 share output o, combine via shfl_xor(32); per-lane h
//   comes from 8 broadcast ds_read_b128 of sh_h).
// gh/gi partials combine through LDS at the gates. 3 lgkm barriers/step.
// amdgpu_waves_per_eu(3,3): 12 waves/CU is this kernel's natural occupancy
// (32 blocks on 256 CUs = 1 block/CU), so cap VGPRs at the 3-wave budget.
// ---------------------------------------------------------------------------
__global__ __attribute__((amdgpu_waves_per_eu(3, 3))) void __launch_bounds__(768)
rssm_scan6(const unsigned* __restrict__ g_whh2, const unsigned* __restrict__ g_wihz,
           const unsigned* __restrict__ g_pr2,  const unsigned* __restrict__ g_po2,
           const float* __restrict__ GIA, const float* __restrict__ POF,
           const float* __restrict__ eps, const float* __restrict__ bhh,
           const float* __restrict__ pr_b, float* __restrict__ out)
{
  __shared__ __align__(16) _Float16 sh_h[128];   // 64 uint pairs
  __shared__ __align__(16) _Float16 sh_z[32];    // 16 uint pairs
  __shared__ float sh_gi[384];    // kh0: GIA + z-dot(lo)
  __shared__ float sh_zi1[384];   // kh1: z-dot(hi)
  __shared__ float sh_gh0[384];   // kh0: bhh + Whh-dot(lo)
  __shared__ float sh_gh1[384];   // kh1: Whh-dot(hi)

  const int b = blockIdx.x, tid = threadIdx.x;
  const int wv = tid >> 6, lane = tid & 63;
  const int kh = (wv >= 6) ? 1 : 0;
  const int nn = tid - (kh ? 384 : 0);

  // ---- persistent weights (k-half) ----
  unsigned whhH[32];
#pragma unroll
  for (int j = 0; j < 32; j++) whhH[j] = g_whh2[(kh*32 + j)*384 + nn];
  unsigned wihzH[8];
#pragma unroll
  for (int j = 0; j < 8; j++) wihzH[j] = g_wihz[(kh*8 + j)*384 + nn];
  const float bhh_i = kh ? 0.f : bhh[nn];

  // ---- prior/post wave roles (kh split within wave: khl = lane>>5) ----
  const bool isPR = (wv == 0) || (wv == 6);
  const bool isPO = (wv == 1) || (wv == 7);
  const int khl = lane >> 5;
  int o = 0;
  if (isPR)      o = ((wv == 6) ? 32 : 0) + (lane & 31);
  else if (isPO) o = ((wv == 7) ? 16 : 0) + ((lane & 16) << 1) + (lane & 15);
  unsigned wpx[32];
#pragma unroll
  for (int j = 0; j < 32; j++) wpx[j] = 0u;
  if (isPR){
#pragma unroll
    for (int j = 0; j < 32; j++) wpx[j] = g_pr2[(khl*32 + j)*64 + o];
  } else if (isPO){
#pragma unroll
    for (int j = 0; j < 32; j++) wpx[j] = g_po2[(khl*32 + j)*64 + o];
  }
  const float prbr = isPR ? pr_b[o] : 0.f;

  // ---- wave-uniform h (k-half) in SGPRs ----
  unsigned hsu[32];
#pragma unroll
  for (int j = 0; j < 32; j++) hsu[j] = 0u;

  // ---- init LDS state ----
  if (tid < 64) ((unsigned*)sh_h)[tid] = 0u;
  if (tid < 16) ((unsigned*)sh_z)[tid] = 0u;

  const bool muLane = isPO && (lane < 16);
  float GIAr = (kh == 0) ? GIA[(size_t)(b*64)*384 + nn] : 0.f;
  float POFr = (isPO && lane < 32) ? POF[(size_t)(b*64)*64 + o] : 0.f;
  float epsr = muLane ? eps[(size_t)(b*64)*32 + o] : 0.f;

  const int OFF_MUP = 0;
  const int OFF_LVP = Bn*Tn*Ln;
  const int OFF_MUQ = 2*Bn*Tn*Ln;
  const int OFF_LVQ = 3*Bn*Tn*Ln;
  const int OFF_H   = 4*Bn*Tn*Ln;
  const int OFF_Z   = 4*Bn*Tn*Ln + Bn*Tn*Hn;

  float hreg = 0.f;
  __syncthreads();

  for (int t = 0; t < Tn; t++){
    const size_t bt = (size_t)b*64 + t;

    // ---- phase A: z-dot half + Whh-dot half ----
    {
      const uint4* Z4 = (const uint4*)sh_z;
      uint4 zlo = Z4[kh*2], zhi = Z4[kh*2 + 1];   // pairs kh*8 .. kh*8+7
      float a0 = (kh == 0) ? GIAr : 0.f, a1 = 0.f;
      a0 = fdot2u(wihzH[0], zlo.x, a0); a1 = fdot2u(wihzH[1], zlo.y, a1);
      a0 = fdot2u(wihzH[2], zlo.z, a0); a1 = fdot2u(wihzH[3], zlo.w, a1);
      a0 = fdot2u(wihzH[4], zhi.x, a0); a1 = fdot2u(wihzH[5], zhi.y, a1);
      a0 = fdot2u(wihzH[6], zhi.z, a0); a1 = fdot2u(wihzH[7], zhi.w, a1);

      float g0 = bhh_i, g1 = 0.f, g2 = 0.f, g3 = 0.f;
#pragma unroll
      for (int j = 0; j < 32; j += 4){
        g0 = fdot2u(whhH[j],   hsu[j],   g0);
        g1 = fdot2u(whhH[j+1], hsu[j+1], g1);
        g2 = fdot2u(whhH[j+2], hsu[j+2], g2);
        g3 = fdot2u(whhH[j+3], hsu[j+3], g3);
      }
      const float gpart = (g0 + g1) + (g2 + g3);
      if (kh == 0){ sh_gi[nn]  = a0 + a1; sh_gh0[nn] = gpart; }
      else        { sh_zi1[nn] = a0 + a1; sh_gh1[nn] = gpart; }
    }
    if (t < Tn-1 && kh == 0) GIAr = GIA[(bt+1)*384 + nn];
    BAR_LDS();

    // ---- phase B: gates (threads 0..127) ----
    if (tid < 128){
      const float gr = (sh_gi[tid]     + sh_zi1[tid])     + (sh_gh0[tid]     + sh_gh1[tid]);
      const float gz = (sh_gi[128+tid] + sh_zi1[128+tid]) + (sh_gh0[128+tid] + sh_gh1[128+tid]);
      const float in_ = sh_gi[256+tid] + sh_zi1[256+tid];
      const float hn_ = sh_gh0[256+tid] + sh_gh1[256+tid];
      const float r  = sigmoid_fast(gr);
      const float zg = sigmoid_fast(gz);
      const float nngate = tanh_fast(fmaf(r, hn_, in_));
      hreg = (1.f - zg)*nngate + zg*hreg;
      sh_h[tid] = (_Float16)hreg;
      out[OFF_H + bt*128 + tid] = hreg;
    }
    BAR_LDS();

    // ---- phase C: hsu refill (all waves) + prior/post (4 waves) ----
    {
      unsigned hv = ((const unsigned*)sh_h)[lane];
#pragma unroll
      for (int j = 0; j < 32; j++) hsu[j] = __builtin_amdgcn_readlane(hv, kh*32 + j);
    }
    if (isPR || isPO){
      // per-lane h (k-half by khl) via broadcast b128 reads
      float p0 = 0.f, p1 = 0.f, p2 = 0.f, p3 = 0.f;
      const uint4* H4 = (const uint4*)sh_h;
#pragma unroll
      for (int j4 = 0; j4 < 8; j4++){
        uint4 hb = H4[khl*8 + j4];
        p0 = fdot2u(wpx[4*j4+0], hb.x, p0);
        p1 = fdot2u(wpx[4*j4+1], hb.y, p1);
        p2 = fdot2u(wpx[4*j4+2], hb.z, p2);
        p3 = fdot2u(wpx[4*j4+3], hb.w, p3);
      }
      float part = (p0 + p1) + (p2 + p3);
      float pfull = part + __shfl_xor(part, 32);
      if (isPR){
        if (lane < 32){
          const float p = pfull + prbr;
          if (wv == 0) out[OFF_MUP + bt*32 + o] = p;
          else         out[OFF_LVP + bt*32 + (o - 32)] = p;
        }
      } else {
        if (lane < 32){
          const float p = pfull + POFr;
          const float q = __shfl_xor(p, 16);
          if (lane < 16){
            out[OFF_MUQ + bt*32 + o] = p;
            const float zz = fmaf(__expf(0.5f*q), epsr, p);
            sh_z[o] = (_Float16)zz;
            out[OFF_Z + bt*32 + o] = zz;
          } else {
            out[OFF_LVQ + bt*32 + (o - 32)] = p;
          }
        }
        if (t < Tn-1){
          if (lane < 32) POFr = POF[(bt+1)*64 + o];
          if (muLane)    epsr = eps[(bt+1)*32 + o];
        }
      }
    }
    BAR_LDS();
  }
}

// ---------------------------------------------------------------------------
extern "C" void kernel_launch(void* const* d_in, const int* in_sizes, int n_in,
                              void* d_out, int out_size, void* d_ws, size_t ws_size,
                              hipStream_t stream)
{
  const float* states = (const float*)d_in[0];
  const float* actions= (const float*)d_in[1];
  const float* c1_w = (const float*)d_in[2];  const float* c1_b = (const float*)d_in[3];
  const float* c2_w = (const float*)d_in[4];  const float* c2_b = (const float*)d_in[5];
  const float* c3_w = (const float*)d_in[6];  const float* c3_b = (const float*)d_in[7];
  const float* c4_w = (const float*)d_in[8];  const float* c4_b = (const float*)d_in[9];
  const float* fc_w = (const float*)d_in[10]; const float* fc_b = (const float*)d_in[11];
  const float* gwih = (const float*)d_in[12]; const float* gwhh = (const float*)d_in[13];
  const float* gbih = (const float*)d_in[14]; const float* gbhh = (const float*)d_in[15];
  const float* pr_w = (const float*)d_in[16]; const float* pr_b = (const float*)d_in[17];
  const float* po_w = (const float*)d_in[18]; const float* po_b = (const float*)d_in[19];
  const float* eps  = (const float*)d_in[20];

  char* p = (char*)d_ws;
  auto alloc = [&](size_t bytes){ char* r = p; p += (bytes + 255) & ~255ULL; return r; };

  unsigned short* statesB = (unsigned short*)alloc((size_t)Nimg*4096*4*2); // NHWC c=4
  unsigned short* act1    = (unsigned short*)alloc((size_t)Nimg*1024*32*2);
  unsigned short* act2    = (unsigned short*)alloc((size_t)Nimg*256*64*2);
  unsigned short* act3    = (unsigned short*)alloc((size_t)Nimg*64*128*2);
  unsigned short* act4    = (unsigned short*)alloc((size_t)Nimg*16*256*2);
  float*          feats   = (float*)alloc((size_t)Nimg*FDn*4);
  unsigned short* w1p     = (unsigned short*)alloc(32*64*2);
  unsigned short* w2p     = (unsigned short*)alloc((size_t)64*512*2);
  unsigned short* w3p     = (unsigned short*)alloc((size_t)128*1024*2);
  unsigned short* w4p     = (unsigned short*)alloc((size_t)256*2048*2);
  unsigned short* wfcp    = (unsigned short*)alloc((size_t)256*4096*2);
  unsigned* g_whh2 = (unsigned*)alloc((size_t)24576*4);
  unsigned* g_wihz = (unsigned*)alloc((size_t)6144*4);
  unsigned* g_pr2  = (unsigned*)alloc((size_t)4096*4);
  unsigned* g_po2  = (unsigned*)alloc((size_t)4096*4);
  float*    GIAb   = (float*)alloc((size_t)786432*4);
  float*    POFb   = (float*)alloc((size_t)Nimg*64*4);

  states_nhwc_kernel<<<Nimg*4096/256, 256, 0, stream>>>(states, statesB);
  prep2_kernel<<<6944, 256, 0, stream>>>(c1_w, c2_w, c3_w, c4_w, fc_w,
                                         gwhh, gwih, pr_w, po_w,
                                         w1p, w2p, w3p, w4p, wfcp,
                                         g_whh2, g_wihz, g_pr2, g_po2);
  gia_kernel<<<Nimg/8, 384, 0, stream>>>(actions, gwih, gbih, GIAb);

  // encoder: NHWC implicit-GEMM MFMA convs (BM=128, swizzled dbuf)
  convN_mfma<4,64,32,32,32,10>  <<< dim3(Nimg*1024/128, 1), 256, 0, stream >>>(statesB, w1p, c1_b, act1);
  convN_mfma<32,32,64,16,64,8>  <<< dim3(Nimg*256/128, 1), 256, 0, stream >>>(act1, w2p, c2_b, act2);
  convN_mfma<64,16,128,8,128,6> <<< dim3(Nimg*64/128, 1), 256, 0, stream >>>(act2, w3p, c3_b, act3);
  convN_mfma<128,8,256,4,128,4> <<< dim3(Nimg*16/128, 2), 256, 0, stream >>>(act3, w4p, c4_b, act4);

  fc_mfma2<<< dim3(Nimg/64, 4), 256, 0, stream >>>(act4, wfcp, fc_b, feats);
  pof_kernel<<< Nimg/8, 256, 0, stream >>>(feats, po_w, po_b, POFb);

  rssm_scan6<<< Bn, 768, 0, stream >>>(g_whh2, g_wihz, g_pr2, g_po2,
                                       GIAb, POFb, eps, gbhh, pr_b, (float*)d_out);
}

// Round 6
// 590.894 us; speedup vs baseline: 1.0069x; 1.0069x over previous
//
#include <hip/hip_runtime.h>
#include <math.h>

#define Bn 32
#define Tn 64
#define An 6
#define Ln 32
#define Hn 128
#define FDn 256
#define Nimg (Bn*Tn)   // 2048

typedef __attribute__((ext_vector_type(8))) short frag_ab;     // 8 bf16
typedef __attribute__((ext_vector_type(4))) float frag_cd;     // 4 fp32
typedef _Float16 h2_t __attribute__((ext_vector_type(2)));

__device__ __forceinline__ float sigmoid_fast(float x){
  return __builtin_amdgcn_rcpf(1.f + __expf(-x));
}
__device__ __forceinline__ float tanh_fast(float x){
  float x2 = fminf(fmaxf(2.f*x, -30.f), 30.f);
  float e = __expf(x2);
  return (e - 1.f) * __builtin_amdgcn_rcpf(e + 1.f);
}

__device__ __forceinline__ unsigned short f2bf(float f){
  unsigned int u = __float_as_uint(f);
  unsigned int r = (u + 0x7fffu + ((u >> 16) & 1u)) >> 16;
  return (unsigned short)r;
}
__device__ __forceinline__ unsigned packh(float a, float b){
  union { h2_t h; unsigned u; } x;
  x.h = (h2_t){(_Float16)a, (_Float16)b};
  return x.u;
}
__device__ __forceinline__ float fdot2u(unsigned a, unsigned b, float c){
  union { unsigned u; h2_t h; } ua, ub;
  ua.u = a; ub.u = b;
#if __has_builtin(__builtin_amdgcn_fdot2)
  return __builtin_amdgcn_fdot2(ua.h, ub.h, c, false);
#else
  return c + (float)ua.h.x*(float)ub.h.x + (float)ua.h.y*(float)ub.h.y;
#endif
}
// barrier without vmcnt drain: global loads/stores in flight stay in flight
#define BAR_LDS() asm volatile("s_waitcnt lgkmcnt(0)\n\ts_barrier" ::: "memory")

// LDS fragment addressing with XOR row swizzle (units: unsigned short)
__device__ __forceinline__ int swz_w(int r, int p){
  return ((r >> 4) << 9) + (p << 7) + ((((r & 15) ^ (p << 2))) << 3);
}
__device__ __forceinline__ int swz_r(int f, int l){
  return (f << 9) + ((l >> 4) << 7) + ((((l & 15) ^ ((l >> 4) << 2))) << 3);
}

// ---------------------------------------------------------------------------
// states: (2048, 3, 64, 64) fp32 NCHW -> (2048, 64, 64, 4) bf16 NHWC (c3 = 0)
// ---------------------------------------------------------------------------
__global__ void __launch_bounds__(256)
states_nhwc_kernel(const float* __restrict__ src, unsigned short* __restrict__ dst)
{
  int idx = blockIdx.x*256 + threadIdx.x;      // 2048*4096
  int n = idx >> 12, pix = idx & 4095;
  const float* s = src + (size_t)n*3*4096 + pix;
  union { unsigned short e[4]; uint2 v; } u;
  u.e[0] = f2bf(s[0]); u.e[1] = f2bf(s[4096]); u.e[2] = f2bf(s[8192]); u.e[3] = 0;
  *(uint2*)(dst + (size_t)idx*4) = u.v;
}

// ---------------------------------------------------------------------------
// merged prep (unchanged layouts):
//   g_whh2 [c(64)][n(384)] : Whh row n, k-pair c
//   g_wihz [c(16)][n(384)] : Wih z-part (k 0..31)
//   g_pr2  [c(64)][o(64)]  : prior rows, k-pair c
//   g_po2  [c(64)][o(64)]  : post h-part rows, k-pair c
// ---------------------------------------------------------------------------
__global__ void __launch_bounds__(256)
prep2_kernel(const float* __restrict__ c1w, const float* __restrict__ c2w,
             const float* __restrict__ c3w, const float* __restrict__ c4w,
             const float* __restrict__ fcw,
             const float* __restrict__ gwhh, const float* __restrict__ gwih,
             const float* __restrict__ prw,  const float* __restrict__ pow_,
             unsigned short* __restrict__ w1p, unsigned short* __restrict__ w2p,
             unsigned short* __restrict__ w3p, unsigned short* __restrict__ w4p,
             unsigned short* __restrict__ wfcp,
             unsigned* __restrict__ g_whh2, unsigned* __restrict__ g_wihz,
             unsigned* __restrict__ g_pr2,  unsigned* __restrict__ g_po2)
{
  const int bid = blockIdx.x, tid = threadIdx.x;
  if (bid < 128){            // c2: (64,32,16) -> [k][tap*32+c]
    int idx = bid*256+tid;
    int k = idx >> 9, r = idx & 511, tap = r >> 5, c = r & 31;
    w2p[idx] = f2bf(c2w[k*512 + c*16 + tap]);
  } else if (bid < 640){     // c3: (128,64,16)
    int idx = (bid-128)*256+tid;
    int k = idx >> 10, r = idx & 1023, tap = r >> 6, c = r & 63;
    w3p[idx] = f2bf(c3w[k*1024 + c*16 + tap]);
  } else if (bid < 2688){    // c4: (256,128,16)
    int idx = (bid-640)*256+tid;
    int k = idx >> 11, r = idx & 2047, tap = r >> 7, c = r & 127;
    w4p[idx] = f2bf(c4w[k*2048 + c*16 + tap]);
  } else if (bid < 6784){    // fc: [o][sp*256+c] = src[o*4096 + c*16 + sp]
    int idx = (bid-2688)*256+tid;
    int o = idx >> 12, r = idx & 4095, sp = r >> 8, c = r & 255;
    wfcp[idx] = f2bf(fcw[o*4096 + c*16 + sp]);
  } else if (bid < 6792){    // c1: (32,3,16) -> [k][tap*4+c], c3=0
    int idx = (bid-6784)*256+tid;
    int k = idx >> 6, r = idx & 63, tap = r >> 2, c = r & 3;
    w1p[idx] = (c < 3) ? f2bf(c1w[k*48 + c*16 + tap]) : (unsigned short)0;
  } else if (bid < 6888){    // whh pack: 24576 uints, [c][n]
    int idx = (bid-6792)*256+tid;
    int c = idx / 384, i = idx - c*384;
    g_whh2[idx] = packh(gwhh[i*128 + 2*c], gwhh[i*128 + 2*c + 1]);
  } else if (bid < 6912){    // wih z-part pack: 6144 uints, [c][n]
    int idx = (bid-6888)*256+tid;
    int c = idx / 384, i = idx - c*384;
    g_wihz[idx] = packh(gwih[i*38 + 2*c], gwih[i*38 + 2*c + 1]);
  } else if (bid < 6928){    // prior pack: 4096 uints, [c][o]
    int idx = (bid-6912)*256+tid;
    int c = idx >> 6, o = idx & 63;
    g_pr2[idx] = packh(prw[o*128 + 2*c], prw[o*128 + 2*c + 1]);
  } else {                   // post h-part pack: 4096 uints, [c][o]
    int idx = (bid-6928)*256+tid;
    int c = idx >> 6, o = idx & 63;
    g_po2[idx] = packh(pow_[o*384 + 2*c], pow_[o*384 + 2*c + 1]);
  }
}

// GIA[bt][n] = bih[n] + a_t . Wih_a[n]   (f32, no recurrence)
__global__ void __launch_bounds__(384)
gia_kernel(const float* __restrict__ actions, const float* __restrict__ gwih,
           const float* __restrict__ bih, float* __restrict__ GIA)
{
  const int tid = threadIdx.x;
  const int bt0 = blockIdx.x * 8;
  __shared__ float ash[48];
  if (tid < 48) ash[tid] = actions[(size_t)bt0*6 + tid];
  float w6[6];
#pragma unroll
  for (int k = 0; k < 6; k++) w6[k] = gwih[tid*38 + 32 + k];
  const float bv = bih[tid];
  __syncthreads();
#pragma unroll
  for (int r = 0; r < 8; r++){
    float v = bv;
#pragma unroll
    for (int k = 0; k < 6; k++) v = fmaf(ash[r*6+k], w6[k], v);
    GIA[(size_t)(bt0 + r)*384 + tid] = v;
  }
}

// POF[bt][o] = po_b[o] + Wpo_f[o] . f_bt   (f32 GEMM 2048x64x256, no recurrence)
__global__ void __launch_bounds__(256)
pof_kernel(const float* __restrict__ feats, const float* __restrict__ po_w,
           const float* __restrict__ po_b, float* __restrict__ POF)
{
  const int tid = threadIdx.x;
  const int bt0 = blockIdx.x * 8;
  __shared__ __align__(16) float fsh[8*256];
  const float4* fsrc = (const float4*)(feats + (size_t)bt0*256);
  ((float4*)fsh)[tid]       = fsrc[tid];
  ((float4*)fsh)[tid + 256] = fsrc[tid + 256];
  __syncthreads();
  const float4* w4 = (const float4*)po_w;
  const float4* f4 = (const float4*)fsh;
#pragma unroll
  for (int i = 0; i < 2; i++){
    int item = tid + i*256;
    int row = item >> 6, o = item & 63;
    float4 acc = {0.f,0.f,0.f,0.f};
#pragma unroll 8
    for (int k = 0; k < 64; k++){
      float4 wv = w4[o*96 + 32 + k];
      float4 fv = f4[row*64 + k];
      acc.x = fmaf(wv.x, fv.x, acc.x);
      acc.y = fmaf(wv.y, fv.y, acc.y);
      acc.z = fmaf(wv.z, fv.z, acc.z);
      acc.w = fmaf(wv.w, fv.w, acc.w);
    }
    POF[(size_t)(bt0 + row)*64 + o] = (acc.x + acc.y) + (acc.z + acc.w) + po_b[o];
  }
}

// ---------------------------------------------------------------------------
// NHWC implicit-GEMM conv (k=4, s=2, p=1), MFMA 16x16x32 bf16.  (unchanged)
// ---------------------------------------------------------------------------
template<int Cin, int IN, int Kout, int OUT, int BN, int LOG_SPB>
__global__ void __launch_bounds__(256)
convN_mfma(const unsigned short* __restrict__ in,
           const unsigned short* __restrict__ wB,
           const float* __restrict__ bias,
           unsigned short* __restrict__ out)
{
  constexpr int SPB = OUT*OUT;
  constexpr int KD  = 16*Cin;
  constexpr int NCH = KD/32;
  constexpr int NFN = BN/32;
  constexpr int BFR = BN/16;
  constexpr int BSL = (BN*4 + 255)/256;
  __shared__ __align__(16) unsigned short Alds[2][8*512];
  __shared__ __align__(16) unsigned short Blds[2][BFR*512];

  const int tid = threadIdx.x;
  const int wave = tid >> 6, lane = tid & 63;
  const unsigned m0 = blockIdx.x * 128;
  const int n0 = blockIdx.y * BN;

  const int p = tid & 3;
  const unsigned short* baseA[2]; int oyA[2], oxA[2]; int AdstI[2];
#pragma unroll
  for (int h = 0; h < 2; h++){
    int r = (tid >> 2) + h*64;
    unsigned m = m0 + r;
    int nimg = m >> LOG_SPB;
    int sp = m & (SPB - 1);
    oyA[h] = sp / OUT; oxA[h] = sp & (OUT - 1);
    baseA[h] = in + (size_t)nimg * IN * IN * Cin;
    AdstI[h] = swz_w(r, p);
  }

  const unsigned short* BsrcH[BSL]; int BdstIH[BSL]; bool bActH[BSL];
#pragma unroll
  for (int h = 0; h < BSL; h++){
    int bn = (tid >> 2) + h*64, pb = tid & 3;
    bActH[h] = bn < BN;
    BsrcH[h] = wB + (size_t)(n0 + bn)*KD + pb*8;
    BdstIH[h] = swz_w(bn, pb);
  }

  const int mhalf = wave >> 1, nhalf = wave & 1;
  frag_cd acc[4][NFN];
#pragma unroll
  for (int i = 0; i < 4; i++)
#pragma unroll
    for (int j = 0; j < NFN; j++) acc[i][j] = (frag_cd){0.f,0.f,0.f,0.f};

  auto loadA = [&](int kt, int h) -> uint4 {
    if constexpr (Cin >= 32){
      constexpr int CPT = Cin/32;
      int tap = kt / CPT;
      int c0 = (kt - tap*CPT)*32;
      int kh = tap >> 2, kw = tap & 3;
      int iy = 2*oyA[h] - 1 + kh;
      int ix = 2*oxA[h] - 1 + kw;
      uint4 v = {0u,0u,0u,0u};
      if ((unsigned)iy < (unsigned)IN && (unsigned)ix < (unsigned)IN)
        v = *(const uint4*)(baseA[h] + ((iy*IN + ix)*Cin + c0 + p*8));
      return v;
    } else {
      int kh = kt*2 + (p >> 1);
      int kw0 = (p & 1)*2;
      int iy = 2*oyA[h] - 1 + kh;
      int ix0 = 2*oxA[h] - 1 + kw0;
      union { uint2 u2[2]; uint4 u4; } v; v.u4 = (uint4){0u,0u,0u,0u};
      bool iyok = (unsigned)iy < (unsigned)IN;
      const unsigned short* rowp = baseA[h] + iy*IN*4;
#pragma unroll
      for (int d = 0; d < 2; d++){
        int ix = ix0 + d;
        if (iyok && (unsigned)ix < (unsigned)IN) v.u2[d] = *(const uint2*)(rowp + ix*4);
      }
      return v.u4;
    }
  };

  const int rdoff = swz_r(0, lane);

  uint4 aR0 = loadA(0,0), aR1 = loadA(0,1);
  uint4 bR[BSL];
#pragma unroll
  for (int h = 0; h < BSL; h++)
    bR[h] = bActH[h] ? *(const uint4*)BsrcH[h] : (uint4){0u,0u,0u,0u};
  *(uint4*)&Alds[0][AdstI[0]] = aR0;
  *(uint4*)&Alds[0][AdstI[1]] = aR1;
#pragma unroll
  for (int h = 0; h < BSL; h++)
    if (bActH[h]) *(uint4*)&Blds[0][BdstIH[h]] = bR[h];
  if (NCH > 1){
    aR0 = loadA(1,0); aR1 = loadA(1,1);
#pragma unroll
    for (int h = 0; h < BSL; h++)
      if (bActH[h]) bR[h] = *(const uint4*)(BsrcH[h] + 32);
  }
  BAR_LDS();

#pragma unroll 2
  for (int kt = 0; kt < NCH; kt++){
    const int cur = kt & 1, nxt = cur ^ 1;
    if (kt + 1 < NCH){
      *(uint4*)&Alds[nxt][AdstI[0]] = aR0;
      *(uint4*)&Alds[nxt][AdstI[1]] = aR1;
#pragma unroll
      for (int h = 0; h < BSL; h++)
        if (bActH[h]) *(uint4*)&Blds[nxt][BdstIH[h]] = bR[h];
      if (kt + 2 < NCH){
        aR0 = loadA(kt+2, 0);
        aR1 = loadA(kt+2, 1);
#pragma unroll
        for (int h = 0; h < BSL; h++)
          if (bActH[h]) bR[h] = *(const uint4*)(BsrcH[h] + (kt+2)*32);
      }
    }
    frag_ab a[4], bf[NFN];
#pragma unroll
    for (int i = 0; i < 4; i++)
      a[i] = *(const frag_ab*)&Alds[cur][(((mhalf<<2) + i) << 9) + rdoff];
#pragma unroll
    for (int j = 0; j < NFN; j++)
      bf[j] = *(const frag_ab*)&Blds[cur][((nhalf*NFN + j) << 9) + rdoff];
#pragma unroll
    for (int i = 0; i < 4; i++)
#pragma unroll
      for (int j = 0; j < NFN; j++)
        acc[i][j] = __builtin_amdgcn_mfma_f32_16x16x32_bf16(a[i], bf[j], acc[i][j], 0, 0, 0);
    BAR_LDS();
  }

  const unsigned mb = m0 + mhalf*64 + ((lane >> 4) << 2);
#pragma unroll
  for (int j = 0; j < NFN; j++){
    const int kg = n0 + nhalf*(NFN*16) + j*16 + (lane & 15);
    const float bv = bias[kg];
#pragma unroll
    for (int i = 0; i < 4; i++){
#pragma unroll
      for (int r = 0; r < 4; r++){
        unsigned mg = mb + i*16 + r;
        out[(size_t)mg*Kout + kg] = f2bf(fmaxf(acc[i][j][r] + bv, 0.f));
      }
    }
  }
}

// ---------------------------------------------------------------------------
// FC GEMM: A (2048 x 4096) bf16, W (256 x 4096) permuted.  (unchanged)
// ---------------------------------------------------------------------------
__global__ void __launch_bounds__(256)
fc_mfma2(const unsigned short* __restrict__ A, const unsigned short* __restrict__ wB,
         const float* __restrict__ bias, float* __restrict__ outF)
{
  constexpr int KD = 4096, NCH = KD/32;
  __shared__ __align__(16) unsigned short Alds[2][4*512];
  __shared__ __align__(16) unsigned short Blds[2][4*512];

  const int tid = threadIdx.x, wave = tid >> 6, lane = tid & 63;
  const int m0 = blockIdx.x * 64, n0 = blockIdx.y * 64;
  const int r = tid >> 2, pc = tid & 3;
  const unsigned short* Asrc = A + (size_t)(m0 + r)*KD + pc*8;
  const unsigned short* Bsrc = wB + (size_t)(n0 + r)*KD + pc*8;
  const int wI = swz_w(r, pc);
  const int mh = wave >> 1, nh = wave & 1;
  const int rdoff = swz_r(0, lane);

  frag_cd acc[2][2];
#pragma unroll
  for (int i = 0; i < 2; i++)
#pragma unroll
    for (int j = 0; j < 2; j++) acc[i][j] = (frag_cd){0.f,0.f,0.f,0.f};

  uint4 aP = *(const uint4*)Asrc, bP = *(const uint4*)Bsrc;
  *(uint4*)&Alds[0][wI] = aP;
  *(uint4*)&Blds[0][wI] = bP;
  aP = *(const uint4*)(Asrc + 32);
  bP = *(const uint4*)(Bsrc + 32);
  BAR_LDS();

#pragma unroll 2
  for (int kt = 0; kt < NCH; kt++){
    const int cur = kt & 1, nxt = cur ^ 1;
    if (kt + 1 < NCH){
      *(uint4*)&Alds[nxt][wI] = aP;
      *(uint4*)&Blds[nxt][wI] = bP;
      if (kt + 2 < NCH){
        aP = *(const uint4*)(Asrc + (kt+2)*32);
        bP = *(const uint4*)(Bsrc + (kt+2)*32);
      }
    }
    frag_ab a[2], b[2];
#pragma unroll
    for (int i = 0; i < 2; i++) a[i] = *(const frag_ab*)&Alds[cur][(((mh<<1)+i) << 9) + rdoff];
#pragma unroll
    for (int j = 0; j < 2; j++) b[j] = *(const frag_ab*)&Blds[cur][(((nh<<1)+j) << 9) + rdoff];
#pragma unroll
    for (int i = 0; i < 2; i++)
#pragma unroll
      for (int j = 0; j < 2; j++)
        acc[i][j] = __builtin_amdgcn_mfma_f32_16x16x32_bf16(a[i], b[j], acc[i][j], 0, 0, 0);
    BAR_LDS();
  }

  const int mb = m0 + mh*32 + ((lane >> 4) << 2);
#pragma unroll
  for (int j = 0; j < 2; j++){
    const int kg = n0 + nh*32 + j*16 + (lane & 15);
    const float bv = bias[kg];
#pragma unroll
    for (int i = 0; i < 2; i++)
#pragma unroll
      for (int rr = 0; rr < 4; rr++)
        outF[(size_t)(mb + i*16 + rr)*256 + kg] = acc[i][j][rr] + bv;
  }
}

// ---------------------------------------------------------------------------
// RSSM scan v8: v6 structure (6 waves, 384 thr, 3 lgkm barriers/step, proven
// 79us) with the spill source removed. v6's static register demand was
// whh2[64]+wihz[16]+wpx[64]+misc ~ 156 VGPR vs 96 physical -> ~60 regs
// spilled to scratch; the spill reloads sat inside phase A's dot chain
// (L2-latency loads, 1.5 waves/SIMD -> unhidden). wpx cost EVERY thread 64
// VGPRs though only waves 0-1 use it (allocation is static). Fix: prior/post
// weights live in LDS (32KB, staged once as uint4 [c4(16)][o(64)]), read in
// phase C via conflict-free contiguous ds_read_b128. Per-thread array demand
// drops to whh2[64]+wihz[16]+misc ~ 92 <= 96 -> Whh stays resident, phase A
// touches no memory. (v7's 12-wave split-k A/B showed wave-count/barrier
// costs dominate over issue throughput -> keep 6 waves.)
// ---------------------------------------------------------------------------
__global__ void __launch_bounds__(384)
rssm_scan7(const unsigned* __restrict__ g_whh2, const unsigned* __restrict__ g_wihz,
           const unsigned* __restrict__ g_pr2,  const unsigned* __restrict__ g_po2,
           const float* __restrict__ GIA, const float* __restrict__ POF,
           const float* __restrict__ eps, const float* __restrict__ bhh,
           const float* __restrict__ pr_b, float* __restrict__ out)
{
  __shared__ __align__(16) _Float16 sh_h[128];
  __shared__ __align__(16) _Float16 sh_z[32];
  __shared__ float sh_gi[384];
  __shared__ float sh_gh[384];
  __shared__ __align__(16) uint4 wpr4[16*64];   // prior W: [c4][o], 16KB
  __shared__ __align__(16) uint4 wpo4[16*64];   // post-h W: [c4][o], 16KB

  const int b = blockIdx.x, tid = threadIdx.x;
  const int wv = tid >> 6, lane = tid & 63;

  // ---- persistent per-thread weights (fit in registers now) ----
  unsigned whh2[64];
#pragma unroll
  for (int c = 0; c < 64; c++) whh2[c] = g_whh2[c*384 + tid];
  unsigned wihz[16];
#pragma unroll
  for (int c = 0; c < 16; c++) wihz[c] = g_wihz[c*384 + tid];
  const float bhh_i = bhh[tid];
  const float prbr = (wv == 0) ? pr_b[lane] : 0.f;

  // ---- stage prior/post weights into LDS (once) ----
  for (int i = tid; i < 1024; i += 384){
    const int c4 = i >> 6, o = i & 63;
    wpr4[i] = (uint4){ g_pr2[(4*c4+0)*64 + o], g_pr2[(4*c4+1)*64 + o],
                       g_pr2[(4*c4+2)*64 + o], g_pr2[(4*c4+3)*64 + o] };
    wpo4[i] = (uint4){ g_po2[(4*c4+0)*64 + o], g_po2[(4*c4+1)*64 + o],
                       g_po2[(4*c4+2)*64 + o], g_po2[(4*c4+3)*64 + o] };
  }

  // ---- wave-uniform h (f16 pairs) in SGPRs ----
  unsigned hsu[64];
#pragma unroll
  for (int c = 0; c < 64; c++) hsu[c] = 0u;

  if (tid < 128) sh_h[tid] = (_Float16)0.f;
  if (tid < 32)  sh_z[tid] = (_Float16)0.f;

  float GIAr = GIA[(size_t)(b*64)*384 + tid];
  float POFr = (wv == 1) ? POF[(size_t)(b*64)*64 + lane] : 0.f;
  float epsr = (wv == 1 && lane < 32) ? eps[(size_t)(b*64)*32 + lane] : 0.f;

  const int OFF_MUP = 0;
  const int OFF_LVP = Bn*Tn*Ln;
  const int OFF_MUQ = 2*Bn*Tn*Ln;
  const int OFF_LVQ = 3*Bn*Tn*Ln;
  const int OFF_H   = 4*Bn*Tn*Ln;
  const int OFF_Z   = 4*Bn*Tn*Ln + Bn*Tn*Hn;

  float hreg = 0.f;
  __syncthreads();

  for (int t = 0; t < Tn; t++){
    const size_t bt = (size_t)b*64 + t;

    // ---- phase A: gi (GIA + z-dot, LDS) and gh (SGPR-h dot, no memory) ----
    {
      const uint4* Z4 = (const uint4*)sh_z;
      uint4 z0 = Z4[0], z1 = Z4[1], z2 = Z4[2], z3 = Z4[3];
      float a0 = GIAr, a1 = 0.f, a2 = 0.f, a3 = 0.f;
      a0 = fdot2u(wihz[0],  z0.x, a0); a1 = fdot2u(wihz[1],  z0.y, a1);
      a2 = fdot2u(wihz[2],  z0.z, a2); a3 = fdot2u(wihz[3],  z0.w, a3);
      a0 = fdot2u(wihz[4],  z1.x, a0); a1 = fdot2u(wihz[5],  z1.y, a1);
      a2 = fdot2u(wihz[6],  z1.z, a2); a3 = fdot2u(wihz[7],  z1.w, a3);
      a0 = fdot2u(wihz[8],  z2.x, a0); a1 = fdot2u(wihz[9],  z2.y, a1);
      a2 = fdot2u(wihz[10], z2.z, a2); a3 = fdot2u(wihz[11], z2.w, a3);
      a0 = fdot2u(wihz[12], z3.x, a0); a1 = fdot2u(wihz[13], z3.y, a1);
      a2 = fdot2u(wihz[14], z3.z, a2); a3 = fdot2u(wihz[15], z3.w, a3);

      float g0 = bhh_i, g1 = 0.f, g2 = 0.f, g3 = 0.f;
#pragma unroll
      for (int c = 0; c < 64; c += 4){
        g0 = fdot2u(whh2[c],   hsu[c],   g0);
        g1 = fdot2u(whh2[c+1], hsu[c+1], g1);
        g2 = fdot2u(whh2[c+2], hsu[c+2], g2);
        g3 = fdot2u(whh2[c+3], hsu[c+3], g3);
      }
      sh_gi[tid] = (a0 + a1) + (a2 + a3);
      sh_gh[tid] = (g0 + g1) + (g2 + g3);
    }
    if (t < Tn-1) GIAr = GIA[(bt+1)*384 + tid];
    BAR_LDS();

    // ---- phase B: gates (threads 0..127) ----
    if (tid < 128){
      const float r  = sigmoid_fast(sh_gi[tid]       + sh_gh[tid]);
      const float zg = sigmoid_fast(sh_gi[128 + tid] + sh_gh[128 + tid]);
      const float nn = tanh_fast(fmaf(r, sh_gh[256 + tid], sh_gi[256 + tid]));
      hreg = (1.f - zg)*nn + zg*hreg;
      sh_h[tid] = (_Float16)hreg;
      out[OFF_H + bt*128 + tid] = hreg;
    }
    BAR_LDS();

    // ---- phase C: refill uniform h; wave0 prior; wave1 post + z ----
    {
      unsigned hv = ((const unsigned*)sh_h)[lane];
#pragma unroll
      for (int c = 0; c < 64; c++) hsu[c] = __builtin_amdgcn_readlane(hv, c);
    }
    if (wv == 0){
      float p0 = prbr, p1 = 0.f, p2 = 0.f, p3 = 0.f;
#pragma unroll
      for (int c4 = 0; c4 < 16; c4++){
        const uint4 w = wpr4[(c4 << 6) + lane];
        p0 = fdot2u(w.x, hsu[4*c4+0], p0);
        p1 = fdot2u(w.y, hsu[4*c4+1], p1);
        p2 = fdot2u(w.z, hsu[4*c4+2], p2);
        p3 = fdot2u(w.w, hsu[4*c4+3], p3);
      }
      const float p = (p0 + p1) + (p2 + p3);
      if (lane < 32) out[OFF_MUP + bt*32 + lane] = p;
      else           out[OFF_LVP + bt*32 + (lane - 32)] = p;
    } else if (wv == 1){
      float p0 = POFr, p1 = 0.f, p2 = 0.f, p3 = 0.f;
#pragma unroll
      for (int c4 = 0; c4 < 16; c4++){
        const uint4 w = wpo4[(c4 << 6) + lane];
        p0 = fdot2u(w.x, hsu[4*c4+0], p0);
        p1 = fdot2u(w.y, hsu[4*c4+1], p1);
        p2 = fdot2u(w.z, hsu[4*c4+2], p2);
        p3 = fdot2u(w.w, hsu[4*c4+3], p3);
      }
      const float p = (p0 + p1) + (p2 + p3);
      const float q = __shfl_xor(p, 32);
      if (lane < 32){
        out[OFF_MUQ + bt*32 + lane] = p;
        const float zz = fmaf(__expf(0.5f*q), epsr, p);
        sh_z[lane] = (_Float16)zz;
        out[OFF_Z + bt*32 + lane] = zz;
      } else {
        out[OFF_LVQ + bt*32 + (lane - 32)] = p;
      }
      if (t < Tn-1){
        POFr = POF[(bt+1)*64 + lane];
        if (lane < 32) epsr = eps[(bt+1)*32 + lane];
      }
    }
    BAR_LDS();
  }
}

// ---------------------------------------------------------------------------
extern "C" void kernel_launch(void* const* d_in, const int* in_sizes, int n_in,
                              void* d_out, int out_size, void* d_ws, size_t ws_size,
                              hipStream_t stream)
{
  const float* states = (const float*)d_in[0];
  const float* actions= (const float*)d_in[1];
  const float* c1_w = (const float*)d_in[2];  const float* c1_b = (const float*)d_in[3];
  const float* c2_w = (const float*)d_in[4];  const float* c2_b = (const float*)d_in[5];
  const float* c3_w = (const float*)d_in[6];  const float* c3_b = (const float*)d_in[7];
  const float* c4_w = (const float*)d_in[8];  const float* c4_b = (const float*)d_in[9];
  const float* fc_w = (const float*)d_in[10]; const float* fc_b = (const float*)d_in[11];
  const float* gwih = (const float*)d_in[12]; const float* gwhh = (const float*)d_in[13];
  const float* gbih = (const float*)d_in[14]; const float* gbhh = (const float*)d_in[15];
  const float* pr_w = (const float*)d_in[16]; const float* pr_b = (const float*)d_in[17];
  const float* po_w = (const float*)d_in[18]; const float* po_b = (const float*)d_in[19];
  const float* eps  = (const float*)d_in[20];

  char* p = (char*)d_ws;
  auto alloc = [&](size_t bytes){ char* r = p; p += (bytes + 255) & ~255ULL; return r; };

  unsigned short* statesB = (unsigned short*)alloc((size_t)Nimg*4096*4*2); // NHWC c=4
  unsigned short* act1    = (unsigned short*)alloc((size_t)Nimg*1024*32*2);
  unsigned short* act2    = (unsigned short*)alloc((size_t)Nimg*256*64*2);
  unsigned short* act3    = (unsigned short*)alloc((size_t)Nimg*64*128*2);
  unsigned short* act4    = (unsigned short*)alloc((size_t)Nimg*16*256*2);
  float*          feats   = (float*)alloc((size_t)Nimg*FDn*4);
  unsigned short* w1p     = (unsigned short*)alloc(32*64*2);
  unsigned short* w2p     = (unsigned short*)alloc((size_t)64*512*2);
  unsigned short* w3p     = (unsigned short*)alloc((size_t)128*1024*2);
  unsigned short* w4p     = (unsigned short*)alloc((size_t)256*2048*2);
  unsigned short* wfcp    = (unsigned short*)alloc((size_t)256*4096*2);
  unsigned* g_whh2 = (unsigned*)alloc((size_t)24576*4);
  unsigned* g_wihz = (unsigned*)alloc((size_t)6144*4);
  unsigned* g_pr2  = (unsigned*)alloc((size_t)4096*4);
  unsigned* g_po2  = (unsigned*)alloc((size_t)4096*4);
  float*    GIAb   = (float*)alloc((size_t)786432*4);
  float*    POFb   = (float*)alloc((size_t)Nimg*64*4);

  states_nhwc_kernel<<<Nimg*4096/256, 256, 0, stream>>>(states, statesB);
  prep2_kernel<<<6944, 256, 0, stream>>>(c1_w, c2_w, c3_w, c4_w, fc_w,
                                         gwhh, gwih, pr_w, po_w,
                                         w1p, w2p, w3p, w4p, wfcp,
                                         g_whh2, g_wihz, g_pr2, g_po2);
  gia_kernel<<<Nimg/8, 384, 0, stream>>>(actions, gwih, gbih, GIAb);

  // encoder: NHWC implicit-GEMM MFMA convs (BM=128, swizzled dbuf)
  convN_mfma<4,64,32,32,32,10>  <<< dim3(Nimg*1024/128, 1), 256, 0, stream >>>(statesB, w1p, c1_b, act1);
  convN_mfma<32,32,64,16,64,8>  <<< dim3(Nimg*256/128, 1), 256, 0, stream >>>(act1, w2p, c2_b, act2);
  convN_mfma<64,16,128,8,128,6> <<< dim3(Nimg*64/128, 1), 256, 0, stream >>>(act2, w3p, c3_b, act3);
  convN_mfma<128,8,256,4,128,4> <<< dim3(Nimg*16/128, 2), 256, 0, stream >>>(act3, w4p, c4_b, act4);

  fc_mfma2<<< dim3(Nimg/64, 4), 256, 0, stream >>>(act4, wfcp, fc_b, feats);
  pof_kernel<<< Nimg/8, 256, 0, stream >>>(feats, po_w, po_b, POFb);

  rssm_scan7<<< Bn, 384, 0, stream >>>(g_whh2, g_wihz, g_pr2, g_po2,
                                       GIAb, POFb, eps, gbhh, pr_b, (float*)d_out);
}